// Round 6
// baseline (551.729 us; speedup 1.0000x reference)
//
#include <hip/hip_runtime.h>
#include <cstdint>

typedef __bf16 bf16;
typedef __attribute__((ext_vector_type(8))) __bf16 bf16x8;
typedef __attribute__((ext_vector_type(4))) __bf16 bf16x4;
typedef __attribute__((ext_vector_type(4))) float f32x4;
typedef __attribute__((ext_vector_type(8))) unsigned short u16x8;

#define AS1C(p) ((const __attribute__((address_space(1))) void*)(p))
#define AS3(p)  ((__attribute__((address_space(3))) void*)(p))

__device__ __forceinline__ float gelu_exact(float v) {
    return 0.5f * v * (1.0f + erff(v * 0.7071067811865476f));
}

// ---------------------------------------------------------------------------
// Weight transpose + fp32->bf16 convert: w [K][N] fp32 -> wt [N][K] bf16
// ---------------------------------------------------------------------------
__global__ __launch_bounds__(256, 1) void wtrans_kernel(
    const float* __restrict__ w, bf16* __restrict__ wt, int K, int N)
{
    __shared__ float tile[64][65];
    const int k0 = blockIdx.y * 64, n0 = blockIdx.x * 64;
    const int tid = threadIdx.x;
    {
        const int kl = tid >> 2, nc = (tid & 3) * 16;
        #pragma unroll
        for (int i = 0; i < 4; ++i) {
            const float4 v = *(const float4*)&w[(size_t)(k0 + kl) * N + n0 + nc + i * 4];
            tile[kl][nc + i * 4 + 0] = v.x;
            tile[kl][nc + i * 4 + 1] = v.y;
            tile[kl][nc + i * 4 + 2] = v.z;
            tile[kl][nc + i * 4 + 3] = v.w;
        }
    }
    __syncthreads();
    {
        const int nl = tid >> 2, kc = (tid & 3) * 16;
        #pragma unroll
        for (int i = 0; i < 4; ++i) {
            bf16x4 o4;
            o4[0] = (bf16)tile[kc + i * 4 + 0][nl];
            o4[1] = (bf16)tile[kc + i * 4 + 1][nl];
            o4[2] = (bf16)tile[kc + i * 4 + 2][nl];
            o4[3] = (bf16)tile[kc + i * 4 + 3][nl];
            *(bf16x4*)&wt[(size_t)(n0 + nl) * K + k0 + kc + i * 4] = o4;
        }
    }
}

__global__ void bias3_kernel(const float* __restrict__ a, const float* __restrict__ b,
                             const float* __restrict__ c, float* __restrict__ o)
{
    const int i = blockIdx.x * 256 + threadIdx.x;
    o[i] = (i < 1024) ? a[i] : (i < 2048 ? b[i - 1024] : c[i - 2048]);
}

// ---------------------------------------------------------------------------
// LayerNorm over rows of 1024 fp32 -> bf16. grid 8192 x 256
// ---------------------------------------------------------------------------
__global__ __launch_bounds__(256, 1) void ln_kernel(
    const float* __restrict__ x, const float* __restrict__ gw,
    const float* __restrict__ bw, bf16* __restrict__ out)
{
    const int row = blockIdx.x, tid = threadIdx.x;
    const float4 v = *(const float4*)&x[(size_t)row * 1024 + tid * 4];
    float s = v.x + v.y + v.z + v.w;
    float q = v.x * v.x + v.y * v.y + v.z * v.z + v.w * v.w;
    #pragma unroll
    for (int off = 32; off > 0; off >>= 1) {
        s += __shfl_xor(s, off);
        q += __shfl_xor(q, off);
    }
    __shared__ float red[8];
    if ((tid & 63) == 0) { red[tid >> 6] = s; red[4 + (tid >> 6)] = q; }
    __syncthreads();
    s = red[0] + red[1] + red[2] + red[3];
    q = red[4] + red[5] + red[6] + red[7];
    const float mu = s * (1.f / 1024.f);
    const float rs = rsqrtf(q * (1.f / 1024.f) - mu * mu + 1e-5f);
    const float4 gg = *(const float4*)&gw[tid * 4];
    const float4 bb = *(const float4*)&bw[tid * 4];
    bf16x4 o4;
    o4[0] = (bf16)((v.x - mu) * rs * gg.x + bb.x);
    o4[1] = (bf16)((v.y - mu) * rs * gg.y + bb.y);
    o4[2] = (bf16)((v.z - mu) * rs * gg.z + bb.z);
    o4[3] = (bf16)((v.w - mu) * rs * gg.w + bb.w);
    *(bf16x4*)&out[(size_t)row * 1024 + tid * 4] = o4;
}

// ---------------------------------------------------------------------------
// Unified GEMM v6: 256 threads (4 waves), per-wave output 128x64, BK=32.
// (BM,BN) = (128,256) or (256,128); BN = 384-BM. LDS: 3 buffers x 24KB =
// 72KB -> 2 blocks/CU = 8 waves = 2 waves/SIMD (VGPR+AGPR ~240 caps at 2).
// Depth-2 prefetch: stage tile t+2 at ph0 of t; end-of-tile vmcnt(6).
// 2 phases/tile x 16 MFMA; A-frags read once (hoisted across phases).
// Swizzle (64B rows): read lb ^= ((lb>>7)&3)<<4; source chunk-permute
// (tid&3)^((tid>>3)&3); linear global_load_lds dest. Raw s_barrier +
// manual lgkmcnt (never drains vmcnt).
// ---------------------------------------------------------------------------
template<int EPI, int BM>
__global__ __launch_bounds__(256, 2) void gemm_v6_kernel(
    const bf16* __restrict__ A, const bf16* __restrict__ BT,
    const float* __restrict__ bias, const float* __restrict__ res,
    void* __restrict__ out, int M, int N, int K)
{
    constexpr int BN = 384 - BM;
    constexpr int ABYTES = BM * 64;
    constexpr int BUFB = 384 * 64;           // 24576
    extern __shared__ char lds[];

    const int tid = threadIdx.x;
    const int lane = tid & 63, wid = tid >> 6;
    const int wr = (BM == 256) ? (wid >> 1) : 0;
    const int wc = (BM == 256) ? (wid & 1) : wid;
    const int j = lane & 15, g = lane >> 4;
    const int srow = tid >> 2;                               // stage row 0..63
    const int skc = ((tid & 3) ^ ((tid >> 3) & 3)) << 3;     // stage k-chunk

    const int nbn = N / BN;
    const int nwg = (M / BM) * nbn;
    const int bid = blockIdx.x;
    const int wg = (bid & 7) * (nwg >> 3) + (bid >> 3);
    const int bm = (wg / nbn) * BM;
    const int bn = (wg % nbn) * BN;

    auto stage = [&](int k0, char* obuf) {
        #pragma unroll
        for (int ga = 0; ga < BM / 64; ++ga) {
            const bf16* src = A + (size_t)(bm + ga * 64 + srow) * K + k0 + skc;
            __builtin_amdgcn_global_load_lds(AS1C(src), AS3(obuf + ga * 4096 + tid * 16), 16, 0, 0);
        }
        #pragma unroll
        for (int gb = 0; gb < BN / 64; ++gb) {
            const bf16* src = BT + (size_t)(bn + gb * 64 + srow) * K + k0 + skc;
            __builtin_amdgcn_global_load_lds(AS1C(src), AS3(obuf + ABYTES + gb * 4096 + tid * 16), 16, 0, 0);
        }
    };

    f32x4 acc[8][4] = {};
    const int NT = K >> 5;

    stage(0, lds);
    stage(32, lds + BUFB);
    asm volatile("s_waitcnt vmcnt(6)" ::: "memory");
    __builtin_amdgcn_s_barrier();

    int cur = 0;
    for (int t = 0; t < NT; ++t) {
        char* buf = lds + cur * BUFB;
        const int nxt2 = (cur + 2 >= 3) ? cur - 1 : cur + 2;

        // ---- phase 0: A frags (8) + B frags 0,1; stage t+2; MFMA 16 ----
        bf16x8 af[8], bfr[2];
        #pragma unroll
        for (int mf = 0; mf < 8; ++mf) {
            const int R = wr * 128 + mf * 16 + j;
            uint32_t lb = (uint32_t)(R * 64 + g * 16);
            lb ^= ((lb >> 7) & 3u) << 4;
            af[mf] = *(const bf16x8*)(buf + lb);
        }
        #pragma unroll
        for (int nf = 0; nf < 2; ++nf) {
            const int R = wc * 64 + nf * 16 + j;
            uint32_t lb = (uint32_t)(R * 64 + g * 16);
            lb ^= ((lb >> 7) & 3u) << 4;
            bfr[nf] = *(const bf16x8*)(buf + ABYTES + lb);
        }
        if (t + 2 < NT) stage((t + 2) << 5, lds + nxt2 * BUFB);
        __builtin_amdgcn_s_barrier();
        asm volatile("s_waitcnt lgkmcnt(0)" ::: "memory");
        __builtin_amdgcn_sched_barrier(0);
        __builtin_amdgcn_s_setprio(1);
        #pragma unroll
        for (int mf = 0; mf < 8; ++mf)
            #pragma unroll
            for (int nf = 0; nf < 2; ++nf)
                acc[mf][nf] = __builtin_amdgcn_mfma_f32_16x16x32_bf16(
                    af[mf], bfr[nf], acc[mf][nf], 0, 0, 0);
        __builtin_amdgcn_s_setprio(0);
        __builtin_amdgcn_s_barrier();

        // ---- phase 1: B frags 2,3; MFMA 16; counted vmcnt; barrier ----
        bf16x8 bfr2[2];
        #pragma unroll
        for (int nf = 0; nf < 2; ++nf) {
            const int R = wc * 64 + (2 + nf) * 16 + j;
            uint32_t lb = (uint32_t)(R * 64 + g * 16);
            lb ^= ((lb >> 7) & 3u) << 4;
            bfr2[nf] = *(const bf16x8*)(buf + ABYTES + lb);
        }
        __builtin_amdgcn_s_barrier();
        asm volatile("s_waitcnt lgkmcnt(0)" ::: "memory");
        __builtin_amdgcn_sched_barrier(0);
        __builtin_amdgcn_s_setprio(1);
        #pragma unroll
        for (int mf = 0; mf < 8; ++mf)
            #pragma unroll
            for (int nf = 0; nf < 2; ++nf)
                acc[mf][2 + nf] = __builtin_amdgcn_mfma_f32_16x16x32_bf16(
                    af[mf], bfr2[nf], acc[mf][2 + nf], 0, 0, 0);
        __builtin_amdgcn_s_setprio(0);
        if (t + 2 < NT) asm volatile("s_waitcnt vmcnt(6)" ::: "memory");
        else            asm volatile("s_waitcnt vmcnt(0)" ::: "memory");
        __builtin_amdgcn_s_barrier();

        cur = (cur + 1 >= 3) ? 0 : cur + 1;
    }

    const int row0 = bm + wr * 128;
    const int col0 = bn + wc * 64;
    #pragma unroll
    for (int nf = 0; nf < 4; ++nf) {
        const int col = col0 + nf * 16 + j;
        const float bs = bias[col];
        #pragma unroll
        for (int mf = 0; mf < 8; ++mf) {
            #pragma unroll
            for (int r = 0; r < 4; ++r) {
                const int row = row0 + mf * 16 + g * 4 + r;
                float v = acc[mf][nf][r] + bs;
                if constexpr (EPI == 2 || EPI == 3) v = gelu_exact(v);
                if constexpr (EPI == 1 || EPI == 3) {
                    v += res[(size_t)row * N + col];
                    ((float*)out)[(size_t)row * N + col] = v;
                } else {
                    ((bf16*)out)[(size_t)row * N + col] = (bf16)v;
                }
            }
        }
    }
}

// ---------------------------------------------------------------------------
// Flash attention v4: no per-iter __syncthreads. V triple-buffered in LDS,
// staged 2 iters ahead; raw s_barrier + lgkmcnt(0) every 2nd iter only
// (vmcnt never drained -> K/V prefetches span iters). Swapped QK^T keeps
// P in PV A-fragment layout; K-frag register double-buffer.
// ---------------------------------------------------------------------------
__device__ __forceinline__ void attn_iter(
    int c, const bf16* __restrict__ Kp, const bf16* __restrict__ Vp,
    uint32_t (&vTu)[3][64][36],
    bf16x8 (&kf)[4][2], bf16x8 (&kfn)[4][2],
    const bf16x8& qf0, const bf16x8& qf1,
    f32x4 (&o)[4], float& mrun, float& lsum,
    int kp, int d0, int jperm, int g, int j)
{
    const f32x4 zero = {0.f, 0.f, 0.f, 0.f};
    const bool pfv = (c + 2 < 16);
    const bool pfk = (c + 1 < 16);

    // V prefetch for block c+2 (LDS write happens after softmax)
    u16x8 r0, r1;
    if (pfv) {
        const size_t vb = (size_t)((c + 2) * 64 + kp) * 3072 + d0;
        r0 = *(const u16x8*)&Vp[vb];
        r1 = *(const u16x8*)&Vp[vb + 3072];
    }

    // QK^T from prefetched K fragments
    f32x4 s[4];
    #pragma unroll
    for (int t = 0; t < 4; ++t) {
        s[t] = __builtin_amdgcn_mfma_f32_16x16x32_bf16(kf[t][0], qf0, zero, 0, 0, 0);
        s[t] = __builtin_amdgcn_mfma_f32_16x16x32_bf16(kf[t][1], qf1, s[t], 0, 0, 0);
    }

    // K prefetch for c+1 (hidden under softmax + PV)
    if (pfk) {
        #pragma unroll
        for (int t = 0; t < 4; ++t) {
            const int key = (c + 1) * 64 + (t >> 1) * 32 + jperm + (t & 1) * 4;
            kfn[t][0] = *(const bf16x8*)&Kp[(size_t)key * 3072 + g * 8];
            kfn[t][1] = *(const bf16x8*)&Kp[(size_t)key * 3072 + 32 + g * 8];
        }
    }

    // online softmax (row = q entirely in-lane, +2 shfl)
    float cur = fmaxf(fmaxf(s[0][0], s[0][1]), fmaxf(s[0][2], s[0][3]));
    #pragma unroll
    for (int t = 1; t < 4; ++t)
        cur = fmaxf(cur, fmaxf(fmaxf(s[t][0], s[t][1]), fmaxf(s[t][2], s[t][3])));
    cur = fmaxf(cur, __shfl_xor(cur, 16));
    cur = fmaxf(cur, __shfl_xor(cur, 32));

    if (!__all(cur - mrun <= 8.0f)) {        // defer-max (THR=8)
        const float mnew = fmaxf(mrun, cur);
        const float alpha = __expf(mrun - mnew);
        float al[4];
        #pragma unroll
        for (int r = 0; r < 4; ++r) al[r] = __shfl(alpha, g * 4 + r);
        #pragma unroll
        for (int dt = 0; dt < 4; ++dt)
            #pragma unroll
            for (int r = 0; r < 4; ++r) o[dt][r] *= al[r];
        lsum *= alpha;
        mrun = mnew;
    }
    float ps = 0.f;
    #pragma unroll
    for (int t = 0; t < 4; ++t)
        #pragma unroll
        for (int r = 0; r < 4; ++r) {
            const float p = __expf(s[t][r] - mrun);
            s[t][r] = p;
            ps += p;
        }
    lsum += ps;

    bf16x8 pa0, pa1;
    #pragma unroll
    for (int r = 0; r < 4; ++r) {
        pa0[r]     = (bf16)s[0][r];
        pa0[4 + r] = (bf16)s[1][r];
        pa1[r]     = (bf16)s[2][r];
        pa1[4 + r] = (bf16)s[3][r];
    }

    // write V block c+2 into buffer (c+2)%3 (read next window, post-barrier)
    if (pfv) {
        const int wb = (c + 2) % 3;
        #pragma unroll
        for (int i = 0; i < 8; ++i)
            vTu[wb][d0 + i][kp >> 1] = (uint32_t)r0[i] | ((uint32_t)r1[i] << 16);
    }

    // O += P V  (reads buffer c%3, written one window ago)
    const int rb = c % 3;
    #pragma unroll
    for (int dt = 0; dt < 4; ++dt) {
        const bf16* vrow = (const bf16*)&vTu[rb][dt * 16 + j][0];
        const bf16x8 vb0 = *(const bf16x8*)(vrow + g * 8);
        const bf16x8 vb1 = *(const bf16x8*)(vrow + 32 + g * 8);
        o[dt] = __builtin_amdgcn_mfma_f32_16x16x32_bf16(pa0, vb0, o[dt], 0, 0, 0);
        o[dt] = __builtin_amdgcn_mfma_f32_16x16x32_bf16(pa1, vb1, o[dt], 0, 0, 0);
    }
}

__global__ __launch_bounds__(256, 1) void attn_kernel(
    const bf16* __restrict__ qkv, bf16* __restrict__ attn, int bh_base)
{
    const int tid = threadIdx.x;
    const int lane = tid & 63, wid = tid >> 6;
    const int j = lane & 15, g = lane >> 4;

    const int lin = blockIdx.x + blockIdx.y * 16;
    const int virt = (lin & 7) * 128 + (lin >> 3);
    const int bh = bh_base + (virt >> 4), qt = virt & 15;
    const int b = bh >> 4, h = bh & 15;
    const int q0 = qt * 64 + wid * 16;

    const bf16* Qp = qkv + (size_t)b * 1024 * 3072 + h * 64;
    const bf16* Kp = Qp + 1024;
    const bf16* Vp = Qp + 2048;

    __shared__ __attribute__((aligned(16))) uint32_t vTu[3][64][36];

    const int kp = (tid & 31) * 2;
    const int d0 = (tid >> 5) * 8;
    // stage V blocks 0 and 1
    #pragma unroll
    for (int pb = 0; pb < 2; ++pb) {
        const u16x8 r0 = *(const u16x8*)&Vp[(size_t)(pb * 64 + kp) * 3072 + d0];
        const u16x8 r1 = *(const u16x8*)&Vp[(size_t)(pb * 64 + kp + 1) * 3072 + d0];
        #pragma unroll
        for (int i = 0; i < 8; ++i)
            vTu[pb][d0 + i][kp >> 1] = (uint32_t)r0[i] | ((uint32_t)r1[i] << 16);
    }

    bf16x8 qf0 = *(const bf16x8*)&Qp[(size_t)(q0 + j) * 3072 + g * 8];
    bf16x8 qf1 = *(const bf16x8*)&Qp[(size_t)(q0 + j) * 3072 + 32 + g * 8];
    #pragma unroll
    for (int e = 0; e < 8; ++e) {
        qf0[e] = (bf16)((float)qf0[e] * 0.03125f);
        qf1[e] = (bf16)((float)qf1[e] * 0.03125f);
    }

    const int jperm = (j >> 2) * 8 + (j & 3);

    f32x4 o[4] = {};
    float mrun = -1e30f, lsum = 0.f;

    bf16x8 kfA[4][2], kfB[4][2];
    #pragma unroll
    for (int t = 0; t < 4; ++t) {
        const int key = (t >> 1) * 32 + jperm + (t & 1) * 4;
        kfA[t][0] = *(const bf16x8*)&Kp[(size_t)key * 3072 + g * 8];
        kfA[t][1] = *(const bf16x8*)&Kp[(size_t)key * 3072 + 32 + g * 8];
    }

    asm volatile("s_waitcnt lgkmcnt(0)" ::: "memory");
    __builtin_amdgcn_s_barrier();

    for (int cc = 0; cc < 16; cc += 2) {
        attn_iter(cc,     Kp, Vp, vTu, kfA, kfB, qf0, qf1, o, mrun, lsum, kp, d0, jperm, g, j);
        attn_iter(cc + 1, Kp, Vp, vTu, kfB, kfA, qf0, qf1, o, mrun, lsum, kp, d0, jperm, g, j);
        asm volatile("s_waitcnt lgkmcnt(0)" ::: "memory");
        __builtin_amdgcn_sched_barrier(0);
        __builtin_amdgcn_s_barrier();
    }

    lsum += __shfl_xor(lsum, 16);
    lsum += __shfl_xor(lsum, 32);
    float inv[4];
    #pragma unroll
    for (int r = 0; r < 4; ++r) inv[r] = 1.0f / __shfl(lsum, g * 4 + r);
    #pragma unroll
    for (int dt = 0; dt < 4; ++dt)
        #pragma unroll
        for (int r = 0; r < 4; ++r)
            attn[(size_t)(b * 1024 + q0 + g * 4 + r) * 1024 + h * 64 + dt * 16 + j] =
                (bf16)(o[dt][r] * inv[r]);
}

// ---------------------------------------------------------------------------
extern "C" void kernel_launch(void* const* d_in, const int* in_sizes, int n_in,
                              void* d_out, int out_size, void* d_ws, size_t ws_size,
                              hipStream_t stream)
{
    const float* x    = (const float*)d_in[0];
    const float* ln1g = (const float*)d_in[1];
    const float* ln1b = (const float*)d_in[2];
    const float* wq   = (const float*)d_in[3];
    const float* bq   = (const float*)d_in[4];
    const float* wk   = (const float*)d_in[5];
    const float* bk   = (const float*)d_in[6];
    const float* wv   = (const float*)d_in[7];
    const float* bv   = (const float*)d_in[8];
    const float* wo   = (const float*)d_in[9];
    const float* bo   = (const float*)d_in[10];
    const float* ln2g = (const float*)d_in[11];
    const float* ln2b = (const float*)d_in[12];
    const float* w1   = (const float*)d_in[13];
    const float* b1   = (const float*)d_in[14];
    const float* w2   = (const float*)d_in[15];
    const float* b2   = (const float*)d_in[16];

    char* ws = (char*)d_ws;
    bf16* wqkvT = (bf16*)ws;  ws += (size_t)3072 * 1024 * 2;
    bf16* woT   = (bf16*)ws;  ws += (size_t)1024 * 1024 * 2;
    bf16* w1T   = (bf16*)ws;  ws += (size_t)4096 * 1024 * 2;
    bf16* w2T   = (bf16*)ws;  ws += (size_t)1024 * 4096 * 2;
    float* bqkv = (float*)ws; ws += (size_t)3072 * 4;
    bf16* h     = (bf16*)ws;  ws += (size_t)8192 * 1024 * 2;
    bf16* qkv   = (bf16*)ws;  ws += (size_t)8192 * 3072 * 2;
    bf16* attn  = (bf16*)ws;  ws += (size_t)8192 * 1024 * 2;
    float* outf = (float*)ws; ws += (size_t)8192 * 1024 * 4;
    bf16* m1    = (bf16*)ws;  ws += (size_t)8192 * 4096 * 2;

    (void)hipFuncSetAttribute((const void*)gemm_v6_kernel<0, 128>,
                              hipFuncAttributeMaxDynamicSharedMemorySize, 73728);
    (void)hipFuncSetAttribute((const void*)gemm_v6_kernel<1, 256>,
                              hipFuncAttributeMaxDynamicSharedMemorySize, 73728);
    (void)hipFuncSetAttribute((const void*)gemm_v6_kernel<2, 128>,
                              hipFuncAttributeMaxDynamicSharedMemorySize, 73728);
    (void)hipFuncSetAttribute((const void*)gemm_v6_kernel<3, 256>,
                              hipFuncAttributeMaxDynamicSharedMemorySize, 73728);

    wtrans_kernel<<<dim3(16, 16), 256, 0, stream>>>(wq, wqkvT,                   1024, 1024);
    wtrans_kernel<<<dim3(16, 16), 256, 0, stream>>>(wk, wqkvT + 1024 * 1024,     1024, 1024);
    wtrans_kernel<<<dim3(16, 16), 256, 0, stream>>>(wv, wqkvT + 2 * 1024 * 1024, 1024, 1024);
    wtrans_kernel<<<dim3(16, 16), 256, 0, stream>>>(wo, woT, 1024, 1024);
    wtrans_kernel<<<dim3(64, 16), 256, 0, stream>>>(w1, w1T, 1024, 4096);
    wtrans_kernel<<<dim3(16, 64), 256, 0, stream>>>(w2, w2T, 4096, 1024);
    bias3_kernel<<<12, 256, 0, stream>>>(bq, bk, bv, bqkv);

    // LN1
    ln_kernel<<<8192, 256, 0, stream>>>(x, ln1g, ln1b, h);
    // QKV projection: BM=128, BN=256 -> 64x12 = 768 blocks
    gemm_v6_kernel<0, 128><<<768, 256, 73728, stream>>>(h, wqkvT, bqkv, nullptr, qkv, 8192, 3072, 1024);
    // attention (2 dispatches for profiler visibility)
    attn_kernel<<<dim3(16, 64), 256, 0, stream>>>(qkv, attn, 0);
    attn_kernel<<<dim3(16, 64), 256, 0, stream>>>(qkv, attn, 64);
    // O projection + bias + residual(x): BM=256, BN=128 -> 32x8 = 256 blocks
    gemm_v6_kernel<1, 256><<<256, 256, 73728, stream>>>(attn, woT, bo, x, outf, 8192, 1024, 1024);
    // LN2
    ln_kernel<<<8192, 256, 0, stream>>>(outf, ln2g, ln2b, h);
    // MLP1: BM=128, BN=256 -> 64x16 = 1024 blocks
    gemm_v6_kernel<2, 128><<<1024, 256, 73728, stream>>>(h, w1T, b1, nullptr, m1, 8192, 4096, 1024);
    // MLP2: BM=256, BN=128 -> 32x8 = 256 blocks, K=4096
    gemm_v6_kernel<3, 256><<<256, 256, 73728, stream>>>(m1, w2T, b2, outf, (float*)d_out, 8192, 1024, 4096);
}

// Round 7
// 511.922 us; speedup vs baseline: 1.0778x; 1.0778x over previous
//
#include <hip/hip_runtime.h>
#include <cstdint>

typedef __bf16 bf16;
typedef __attribute__((ext_vector_type(8))) __bf16 bf16x8;
typedef __attribute__((ext_vector_type(4))) __bf16 bf16x4;
typedef __attribute__((ext_vector_type(4))) float f32x4;
typedef __attribute__((ext_vector_type(8))) unsigned short u16x8;

#define AS1C(p) ((const __attribute__((address_space(1))) void*)(p))
#define AS3(p)  ((__attribute__((address_space(3))) void*)(p))

__device__ __forceinline__ float gelu_exact(float v) {
    return 0.5f * v * (1.0f + erff(v * 0.7071067811865476f));
}

// ---------------------------------------------------------------------------
// Weight transpose + fp32->bf16 convert: w [K][N] fp32 -> wt [N][K] bf16
// ---------------------------------------------------------------------------
__global__ __launch_bounds__(256, 1) void wtrans_kernel(
    const float* __restrict__ w, bf16* __restrict__ wt, int K, int N)
{
    __shared__ float tile[64][65];
    const int k0 = blockIdx.y * 64, n0 = blockIdx.x * 64;
    const int tid = threadIdx.x;
    {
        const int kl = tid >> 2, nc = (tid & 3) * 16;
        #pragma unroll
        for (int i = 0; i < 4; ++i) {
            const float4 v = *(const float4*)&w[(size_t)(k0 + kl) * N + n0 + nc + i * 4];
            tile[kl][nc + i * 4 + 0] = v.x;
            tile[kl][nc + i * 4 + 1] = v.y;
            tile[kl][nc + i * 4 + 2] = v.z;
            tile[kl][nc + i * 4 + 3] = v.w;
        }
    }
    __syncthreads();
    {
        const int nl = tid >> 2, kc = (tid & 3) * 16;
        #pragma unroll
        for (int i = 0; i < 4; ++i) {
            bf16x4 o4;
            o4[0] = (bf16)tile[kc + i * 4 + 0][nl];
            o4[1] = (bf16)tile[kc + i * 4 + 1][nl];
            o4[2] = (bf16)tile[kc + i * 4 + 2][nl];
            o4[3] = (bf16)tile[kc + i * 4 + 3][nl];
            *(bf16x4*)&wt[(size_t)(n0 + nl) * K + k0 + kc + i * 4] = o4;
        }
    }
}

__global__ void bias3_kernel(const float* __restrict__ a, const float* __restrict__ b,
                             const float* __restrict__ c, float* __restrict__ o)
{
    const int i = blockIdx.x * 256 + threadIdx.x;
    o[i] = (i < 1024) ? a[i] : (i < 2048 ? b[i - 1024] : c[i - 2048]);
}

// ---------------------------------------------------------------------------
// LayerNorm over rows of 1024 fp32 -> bf16. grid 8192 x 256
// ---------------------------------------------------------------------------
__global__ __launch_bounds__(256, 1) void ln_kernel(
    const float* __restrict__ x, const float* __restrict__ gw,
    const float* __restrict__ bw, bf16* __restrict__ out)
{
    const int row = blockIdx.x, tid = threadIdx.x;
    const float4 v = *(const float4*)&x[(size_t)row * 1024 + tid * 4];
    float s = v.x + v.y + v.z + v.w;
    float q = v.x * v.x + v.y * v.y + v.z * v.z + v.w * v.w;
    #pragma unroll
    for (int off = 32; off > 0; off >>= 1) {
        s += __shfl_xor(s, off);
        q += __shfl_xor(q, off);
    }
    __shared__ float red[8];
    if ((tid & 63) == 0) { red[tid >> 6] = s; red[4 + (tid >> 6)] = q; }
    __syncthreads();
    s = red[0] + red[1] + red[2] + red[3];
    q = red[4] + red[5] + red[6] + red[7];
    const float mu = s * (1.f / 1024.f);
    const float rs = rsqrtf(q * (1.f / 1024.f) - mu * mu + 1e-5f);
    const float4 gg = *(const float4*)&gw[tid * 4];
    const float4 bb = *(const float4*)&bw[tid * 4];
    bf16x4 o4;
    o4[0] = (bf16)((v.x - mu) * rs * gg.x + bb.x);
    o4[1] = (bf16)((v.y - mu) * rs * gg.y + bb.y);
    o4[2] = (bf16)((v.z - mu) * rs * gg.z + bb.z);
    o4[3] = (bf16)((v.w - mu) * rs * gg.w + bb.w);
    *(bf16x4*)&out[(size_t)row * 1024 + tid * 4] = o4;
}

// ---------------------------------------------------------------------------
// GEMM v7: 512 threads (8 waves, 2 waves/SIMD ALWAYS — even at grid=256).
// BM=256, BN=128, per-wave 64x64 (4wr x 2wc), BK=64.
// LDS: 3 buffers x 48KB = 144KB -> 1 block/CU, 8 waves.
// Depth-2 prefetch (stage t+2 at ph0 of t), end-of-tile vmcnt(6) counted.
// 2 phases/tile x 16 MFMA; A-frags hoisted across both phases.
// Swizzle (128B rows): read byte bits 4-6 ^= bits 8-10 (row bits 1-3);
// source k-chunk permute (tid&7)^((tid>>4)&7); linear global_load_lds dest.
// ---------------------------------------------------------------------------
template<int EPI>
__global__ __launch_bounds__(512, 2) void gemm_v7_kernel(
    const bf16* __restrict__ A, const bf16* __restrict__ BT,
    const float* __restrict__ bias, const float* __restrict__ res,
    void* __restrict__ out, int M, int N, int K)
{
    constexpr int ABYTES = 256 * 128;        // 32768
    constexpr int BUFB = 384 * 128;          // 49152
    extern __shared__ char lds[];

    const int tid = threadIdx.x;
    const int lane = tid & 63, wid = tid >> 6;
    const int wr = wid >> 1, wc = wid & 1;
    const int j = lane & 15, g = lane >> 4;
    const int skc = ((tid & 7) ^ ((tid >> 4) & 7)) << 3;   // source k-chunk (elems)

    const int nbn = N >> 7;
    const int nwg = (M >> 8) * nbn;
    const int bid = blockIdx.x;
    const int wg = (bid & 7) * (nwg >> 3) + (bid >> 3);
    const int bm = (wg / nbn) << 8;
    const int bn = (wg % nbn) << 7;

    auto stage = [&](int k0, char* obuf) {
        #pragma unroll
        for (int ga = 0; ga < 4; ++ga) {
            const bf16* src = A + (size_t)(bm + ga * 64 + (tid >> 3)) * K + k0 + skc;
            __builtin_amdgcn_global_load_lds(AS1C(src), AS3(obuf + ga * 8192 + tid * 16), 16, 0, 0);
        }
        #pragma unroll
        for (int gb = 0; gb < 2; ++gb) {
            const bf16* src = BT + (size_t)(bn + gb * 64 + (tid >> 3)) * K + k0 + skc;
            __builtin_amdgcn_global_load_lds(AS1C(src), AS3(obuf + ABYTES + gb * 8192 + tid * 16), 16, 0, 0);
        }
    };

    f32x4 acc[4][4] = {};
    const int NT = K >> 6;

    stage(0, lds);
    stage(64, lds + BUFB);
    asm volatile("s_waitcnt vmcnt(6)" ::: "memory");
    __builtin_amdgcn_s_barrier();

    int cur = 0;
    for (int t = 0; t < NT; ++t) {
        char* buf = lds + cur * BUFB;
        const int nxt2 = (cur >= 1) ? cur - 1 : 2;

        // ---- phase 0: A frags (8 reads, hoisted) + B frags 0,1; stage t+2 ----
        bf16x8 af[4][2], bfr[2][2];
        #pragma unroll
        for (int mf = 0; mf < 4; ++mf)
            #pragma unroll
            for (int ks = 0; ks < 2; ++ks) {
                const int R = wr * 64 + mf * 16 + j;
                uint32_t lb = (uint32_t)(R * 128 + ks * 64 + g * 16);
                lb ^= (lb >> 4) & 0x70u;
                af[mf][ks] = *(const bf16x8*)(buf + lb);
            }
        #pragma unroll
        for (int nf = 0; nf < 2; ++nf)
            #pragma unroll
            for (int ks = 0; ks < 2; ++ks) {
                const int R = wc * 64 + nf * 16 + j;
                uint32_t lb = (uint32_t)(R * 128 + ks * 64 + g * 16);
                lb ^= (lb >> 4) & 0x70u;
                bfr[nf][ks] = *(const bf16x8*)(buf + ABYTES + lb);
            }
        if (t + 2 < NT) stage((t + 2) << 6, lds + nxt2 * BUFB);
        __builtin_amdgcn_s_barrier();
        asm volatile("s_waitcnt lgkmcnt(0)" ::: "memory");
        __builtin_amdgcn_sched_barrier(0);
        __builtin_amdgcn_s_setprio(1);
        #pragma unroll
        for (int mf = 0; mf < 4; ++mf)
            #pragma unroll
            for (int nf = 0; nf < 2; ++nf)
                #pragma unroll
                for (int ks = 0; ks < 2; ++ks)
                    acc[mf][nf] = __builtin_amdgcn_mfma_f32_16x16x32_bf16(
                        af[mf][ks], bfr[nf][ks], acc[mf][nf], 0, 0, 0);
        __builtin_amdgcn_s_setprio(0);
        __builtin_amdgcn_s_barrier();

        // ---- phase 1: B frags 2,3; counted vmcnt at tile end ----
        bf16x8 bfr2[2][2];
        #pragma unroll
        for (int nf = 0; nf < 2; ++nf)
            #pragma unroll
            for (int ks = 0; ks < 2; ++ks) {
                const int R = wc * 64 + (2 + nf) * 16 + j;
                uint32_t lb = (uint32_t)(R * 128 + ks * 64 + g * 16);
                lb ^= (lb >> 4) & 0x70u;
                bfr2[nf][ks] = *(const bf16x8*)(buf + ABYTES + lb);
            }
        __builtin_amdgcn_s_barrier();
        asm volatile("s_waitcnt lgkmcnt(0)" ::: "memory");
        __builtin_amdgcn_sched_barrier(0);
        __builtin_amdgcn_s_setprio(1);
        #pragma unroll
        for (int mf = 0; mf < 4; ++mf)
            #pragma unroll
            for (int nf = 0; nf < 2; ++nf)
                #pragma unroll
                for (int ks = 0; ks < 2; ++ks)
                    acc[mf][2 + nf] = __builtin_amdgcn_mfma_f32_16x16x32_bf16(
                        af[mf][ks], bfr2[nf][ks], acc[mf][2 + nf], 0, 0, 0);
        __builtin_amdgcn_s_setprio(0);
        if (t + 2 < NT) asm volatile("s_waitcnt vmcnt(6)" ::: "memory");
        else            asm volatile("s_waitcnt vmcnt(0)" ::: "memory");
        __builtin_amdgcn_s_barrier();

        cur = (cur == 2) ? 0 : cur + 1;
    }

    const int row0 = bm + wr * 64;
    const int col0 = bn + wc * 64;
    #pragma unroll
    for (int nf = 0; nf < 4; ++nf) {
        const int col = col0 + nf * 16 + j;
        const float bs = bias[col];
        #pragma unroll
        for (int mf = 0; mf < 4; ++mf) {
            #pragma unroll
            for (int r = 0; r < 4; ++r) {
                const int row = row0 + mf * 16 + g * 4 + r;
                float v = acc[mf][nf][r] + bs;
                if constexpr (EPI == 2 || EPI == 3) v = gelu_exact(v);
                if constexpr (EPI == 1 || EPI == 3) {
                    v += res[(size_t)row * N + col];
                    ((float*)out)[(size_t)row * N + col] = v;
                } else {
                    ((bf16*)out)[(size_t)row * N + col] = (bf16)v;
                }
            }
        }
    }
}

// ---------------------------------------------------------------------------
// Flash attention v5: like v4 but 4 V-buffers (race-free: window write-set
// {2,3} disjoint from read-set {0,1} mod 4). Barrier every 2 iters only.
// ---------------------------------------------------------------------------
__device__ __forceinline__ void attn_iter(
    int c, const bf16* __restrict__ Kp, const bf16* __restrict__ Vp,
    uint32_t (&vTu)[4][64][36],
    bf16x8 (&kf)[4][2], bf16x8 (&kfn)[4][2],
    const bf16x8& qf0, const bf16x8& qf1,
    f32x4 (&o)[4], float& mrun, float& lsum,
    int kp, int d0, int jperm, int g, int j)
{
    const f32x4 zero = {0.f, 0.f, 0.f, 0.f};
    const bool pfv = (c + 2 < 16);
    const bool pfk = (c + 1 < 16);

    u16x8 r0, r1;
    if (pfv) {
        const size_t vb = (size_t)((c + 2) * 64 + kp) * 3072 + d0;
        r0 = *(const u16x8*)&Vp[vb];
        r1 = *(const u16x8*)&Vp[vb + 3072];
    }

    f32x4 s[4];
    #pragma unroll
    for (int t = 0; t < 4; ++t) {
        s[t] = __builtin_amdgcn_mfma_f32_16x16x32_bf16(kf[t][0], qf0, zero, 0, 0, 0);
        s[t] = __builtin_amdgcn_mfma_f32_16x16x32_bf16(kf[t][1], qf1, s[t], 0, 0, 0);
    }

    if (pfk) {
        #pragma unroll
        for (int t = 0; t < 4; ++t) {
            const int key = (c + 1) * 64 + (t >> 1) * 32 + jperm + (t & 1) * 4;
            kfn[t][0] = *(const bf16x8*)&Kp[(size_t)key * 3072 + g * 8];
            kfn[t][1] = *(const bf16x8*)&Kp[(size_t)key * 3072 + 32 + g * 8];
        }
    }

    float cur = fmaxf(fmaxf(s[0][0], s[0][1]), fmaxf(s[0][2], s[0][3]));
    #pragma unroll
    for (int t = 1; t < 4; ++t)
        cur = fmaxf(cur, fmaxf(fmaxf(s[t][0], s[t][1]), fmaxf(s[t][2], s[t][3])));
    cur = fmaxf(cur, __shfl_xor(cur, 16));
    cur = fmaxf(cur, __shfl_xor(cur, 32));

    if (!__all(cur - mrun <= 8.0f)) {
        const float mnew = fmaxf(mrun, cur);
        const float alpha = __expf(mrun - mnew);
        float al[4];
        #pragma unroll
        for (int r = 0; r < 4; ++r) al[r] = __shfl(alpha, g * 4 + r);
        #pragma unroll
        for (int dt = 0; dt < 4; ++dt)
            #pragma unroll
            for (int r = 0; r < 4; ++r) o[dt][r] *= al[r];
        lsum *= alpha;
        mrun = mnew;
    }
    float ps = 0.f;
    #pragma unroll
    for (int t = 0; t < 4; ++t)
        #pragma unroll
        for (int r = 0; r < 4; ++r) {
            const float p = __expf(s[t][r] - mrun);
            s[t][r] = p;
            ps += p;
        }
    lsum += ps;

    bf16x8 pa0, pa1;
    #pragma unroll
    for (int r = 0; r < 4; ++r) {
        pa0[r]     = (bf16)s[0][r];
        pa0[4 + r] = (bf16)s[1][r];
        pa1[r]     = (bf16)s[2][r];
        pa1[4 + r] = (bf16)s[3][r];
    }

    if (pfv) {
        const int wb = (c + 2) & 3;
        #pragma unroll
        for (int i = 0; i < 8; ++i)
            vTu[wb][d0 + i][kp >> 1] = (uint32_t)r0[i] | ((uint32_t)r1[i] << 16);
    }

    const int rb = c & 3;
    #pragma unroll
    for (int dt = 0; dt < 4; ++dt) {
        const bf16* vrow = (const bf16*)&vTu[rb][dt * 16 + j][0];
        const bf16x8 vb0 = *(const bf16x8*)(vrow + g * 8);
        const bf16x8 vb1 = *(const bf16x8*)(vrow + 32 + g * 8);
        o[dt] = __builtin_amdgcn_mfma_f32_16x16x32_bf16(pa0, vb0, o[dt], 0, 0, 0);
        o[dt] = __builtin_amdgcn_mfma_f32_16x16x32_bf16(pa1, vb1, o[dt], 0, 0, 0);
    }
}

__global__ __launch_bounds__(256, 1) void attn_kernel(
    const bf16* __restrict__ qkv, bf16* __restrict__ attn, int bh_base)
{
    const int tid = threadIdx.x;
    const int lane = tid & 63, wid = tid >> 6;
    const int j = lane & 15, g = lane >> 4;

    const int lin = blockIdx.x + blockIdx.y * 16;
    const int virt = (lin & 7) * 128 + (lin >> 3);
    const int bh = bh_base + (virt >> 4), qt = virt & 15;
    const int b = bh >> 4, h = bh & 15;
    const int q0 = qt * 64 + wid * 16;

    const bf16* Qp = qkv + (size_t)b * 1024 * 3072 + h * 64;
    const bf16* Kp = Qp + 1024;
    const bf16* Vp = Qp + 2048;

    __shared__ __attribute__((aligned(16))) uint32_t vTu[4][64][36];

    const int kp = (tid & 31) * 2;
    const int d0 = (tid >> 5) * 8;
    #pragma unroll
    for (int pb = 0; pb < 2; ++pb) {
        const u16x8 r0 = *(const u16x8*)&Vp[(size_t)(pb * 64 + kp) * 3072 + d0];
        const u16x8 r1 = *(const u16x8*)&Vp[(size_t)(pb * 64 + kp + 1) * 3072 + d0];
        #pragma unroll
        for (int i = 0; i < 8; ++i)
            vTu[pb][d0 + i][kp >> 1] = (uint32_t)r0[i] | ((uint32_t)r1[i] << 16);
    }

    bf16x8 qf0 = *(const bf16x8*)&Qp[(size_t)(q0 + j) * 3072 + g * 8];
    bf16x8 qf1 = *(const bf16x8*)&Qp[(size_t)(q0 + j) * 3072 + 32 + g * 8];
    #pragma unroll
    for (int e = 0; e < 8; ++e) {
        qf0[e] = (bf16)((float)qf0[e] * 0.03125f);
        qf1[e] = (bf16)((float)qf1[e] * 0.03125f);
    }

    const int jperm = (j >> 2) * 8 + (j & 3);

    f32x4 o[4] = {};
    float mrun = -1e30f, lsum = 0.f;

    bf16x8 kfA[4][2], kfB[4][2];
    #pragma unroll
    for (int t = 0; t < 4; ++t) {
        const int key = (t >> 1) * 32 + jperm + (t & 1) * 4;
        kfA[t][0] = *(const bf16x8*)&Kp[(size_t)key * 3072 + g * 8];
        kfA[t][1] = *(const bf16x8*)&Kp[(size_t)key * 3072 + 32 + g * 8];
    }

    asm volatile("s_waitcnt lgkmcnt(0)" ::: "memory");
    __builtin_amdgcn_s_barrier();

    for (int cc = 0; cc < 16; cc += 2) {
        attn_iter(cc,     Kp, Vp, vTu, kfA, kfB, qf0, qf1, o, mrun, lsum, kp, d0, jperm, g, j);
        attn_iter(cc + 1, Kp, Vp, vTu, kfB, kfA, qf0, qf1, o, mrun, lsum, kp, d0, jperm, g, j);
        asm volatile("s_waitcnt lgkmcnt(0)" ::: "memory");
        __builtin_amdgcn_sched_barrier(0);
        __builtin_amdgcn_s_barrier();
    }

    lsum += __shfl_xor(lsum, 16);
    lsum += __shfl_xor(lsum, 32);
    float inv[4];
    #pragma unroll
    for (int r = 0; r < 4; ++r) inv[r] = 1.0f / __shfl(lsum, g * 4 + r);
    #pragma unroll
    for (int dt = 0; dt < 4; ++dt)
        #pragma unroll
        for (int r = 0; r < 4; ++r)
            attn[(size_t)(b * 1024 + q0 + g * 4 + r) * 1024 + h * 64 + dt * 16 + j] =
                (bf16)(o[dt][r] * inv[r]);
}

// ---------------------------------------------------------------------------
extern "C" void kernel_launch(void* const* d_in, const int* in_sizes, int n_in,
                              void* d_out, int out_size, void* d_ws, size_t ws_size,
                              hipStream_t stream)
{
    const float* x    = (const float*)d_in[0];
    const float* ln1g = (const float*)d_in[1];
    const float* ln1b = (const float*)d_in[2];
    const float* wq   = (const float*)d_in[3];
    const float* bq   = (const float*)d_in[4];
    const float* wk   = (const float*)d_in[5];
    const float* bk   = (const float*)d_in[6];
    const float* wv   = (const float*)d_in[7];
    const float* bv   = (const float*)d_in[8];
    const float* wo   = (const float*)d_in[9];
    const float* bo   = (const float*)d_in[10];
    const float* ln2g = (const float*)d_in[11];
    const float* ln2b = (const float*)d_in[12];
    const float* w1   = (const float*)d_in[13];
    const float* b1   = (const float*)d_in[14];
    const float* w2   = (const float*)d_in[15];
    const float* b2   = (const float*)d_in[16];

    char* ws = (char*)d_ws;
    bf16* wqkvT = (bf16*)ws;  ws += (size_t)3072 * 1024 * 2;
    bf16* woT   = (bf16*)ws;  ws += (size_t)1024 * 1024 * 2;
    bf16* w1T   = (bf16*)ws;  ws += (size_t)4096 * 1024 * 2;
    bf16* w2T   = (bf16*)ws;  ws += (size_t)1024 * 4096 * 2;
    float* bqkv = (float*)ws; ws += (size_t)3072 * 4;
    bf16* h     = (bf16*)ws;  ws += (size_t)8192 * 1024 * 2;
    bf16* qkv   = (bf16*)ws;  ws += (size_t)8192 * 3072 * 2;
    bf16* attn  = (bf16*)ws;  ws += (size_t)8192 * 1024 * 2;
    float* outf = (float*)ws; ws += (size_t)8192 * 1024 * 4;
    bf16* m1    = (bf16*)ws;  ws += (size_t)8192 * 4096 * 2;

    (void)hipFuncSetAttribute((const void*)gemm_v7_kernel<0>,
                              hipFuncAttributeMaxDynamicSharedMemorySize, 147456);
    (void)hipFuncSetAttribute((const void*)gemm_v7_kernel<1>,
                              hipFuncAttributeMaxDynamicSharedMemorySize, 147456);
    (void)hipFuncSetAttribute((const void*)gemm_v7_kernel<2>,
                              hipFuncAttributeMaxDynamicSharedMemorySize, 147456);
    (void)hipFuncSetAttribute((const void*)gemm_v7_kernel<3>,
                              hipFuncAttributeMaxDynamicSharedMemorySize, 147456);

    wtrans_kernel<<<dim3(16, 16), 256, 0, stream>>>(wq, wqkvT,                   1024, 1024);
    wtrans_kernel<<<dim3(16, 16), 256, 0, stream>>>(wk, wqkvT + 1024 * 1024,     1024, 1024);
    wtrans_kernel<<<dim3(16, 16), 256, 0, stream>>>(wv, wqkvT + 2 * 1024 * 1024, 1024, 1024);
    wtrans_kernel<<<dim3(16, 16), 256, 0, stream>>>(wo, woT, 1024, 1024);
    wtrans_kernel<<<dim3(64, 16), 256, 0, stream>>>(w1, w1T, 1024, 4096);
    wtrans_kernel<<<dim3(16, 64), 256, 0, stream>>>(w2, w2T, 4096, 1024);
    bias3_kernel<<<12, 256, 0, stream>>>(bq, bk, bv, bqkv);

    // LN1
    ln_kernel<<<8192, 256, 0, stream>>>(x, ln1g, ln1b, h);
    // QKV projection: 32 x 24 = 768 blocks
    gemm_v7_kernel<0><<<768, 512, 147456, stream>>>(h, wqkvT, bqkv, nullptr, qkv, 8192, 3072, 1024);
    // attention (2 dispatches for profiler visibility)
    attn_kernel<<<dim3(16, 64), 256, 0, stream>>>(qkv, attn, 0);
    attn_kernel<<<dim3(16, 64), 256, 0, stream>>>(qkv, attn, 64);
    // O projection + bias + residual(x): 32 x 8 = 256 blocks
    gemm_v7_kernel<1><<<256, 512, 147456, stream>>>(attn, woT, bo, x, outf, 8192, 1024, 1024);
    // LN2
    ln_kernel<<<8192, 256, 0, stream>>>(outf, ln2g, ln2b, h);
    // MLP1: 32 x 32 = 1024 blocks
    gemm_v7_kernel<2><<<1024, 512, 147456, stream>>>(h, w1T, b1, nullptr, m1, 8192, 4096, 1024);
    // MLP2: 32 x 8 = 256 blocks, K=4096
    gemm_v7_kernel<3><<<256, 512, 147456, stream>>>(m1, w2T, b2, outf, (float*)d_out, 8192, 1024, 4096);
}